// Round 8
// baseline (295.987 us; speedup 1.0000x reference)
//
#include <hip/hip_runtime.h>

#define H_DIM 768
#define C_DIM 512
#define L_DIM 256
#define S_DIM 2048
#define B_DIM 16

#define IA_STRIDE 520   // 512 + 8: lane stride 1040B = 260 dw = 4 mod 32 banks
#define ATTN_STRIDE 264 // 256 + 8: lane stride 528B = 132 dw = 4 mod 32 banks
#define XP_STRIDE 776   // 768 + 8 (f16): row stride 1552B, 16B-aligned, 2-way conflict (free)

typedef __attribute__((ext_vector_type(8))) short short8;
typedef __attribute__((ext_vector_type(4))) float f32x4;
typedef __attribute__((ext_vector_type(2))) __fp16 half2v;   // cvt_pkrtz return type

#define MFMA_F16(a, b, c) __builtin_amdgcn_mfma_f32_16x16x32_f16((a), (b), (c), 0, 0, 0)

__device__ __forceinline__ unsigned short f2h(float f) {
    _Float16 h = (_Float16)f;
    return __builtin_bit_cast(unsigned short, h);
}
__device__ __forceinline__ float h2f(unsigned short u) {
    _Float16 h = __builtin_bit_cast(_Float16, u);
    return (float)h;
}
__device__ __forceinline__ float sigmoid_f(float x) { return 1.0f / (1.0f + __expf(-x)); }

// load 8 consecutive f32, convert to packed f16 frag via v_cvt_pkrtz
__device__ __forceinline__ short8 cvt8(const float* p) {
    const float4* q = (const float4*)(const void*)p;
    float4 u = q[0], v = q[1];
    half2v h0 = __builtin_amdgcn_cvt_pkrtz(u.x, u.y);
    half2v h1 = __builtin_amdgcn_cvt_pkrtz(u.z, u.w);
    half2v h2 = __builtin_amdgcn_cvt_pkrtz(v.x, v.y);
    half2v h3 = __builtin_amdgcn_cvt_pkrtz(v.z, v.w);
    int4 pk = { __builtin_bit_cast(int, h0), __builtin_bit_cast(int, h1),
                __builtin_bit_cast(int, h2), __builtin_bit_cast(int, h3) };
    return __builtin_bit_cast(short8, pk);
}

// ---------------------------------------------------------------------------
// Frag layouts (one wave frag load = 64 lanes x 16 B = 1 KB contiguous):
//   B operand M[n][k]: lane = (n&15) | (((k>>3)&3)<<4), j = k&7
//     W  (n 32 ct, k 24 kt): frag = ((ct>>3)*24 + kt)*8 + (ct&7)
//     la (n 16 lt, k 16 kt): frag = ((lt>>2)*16 + kt)*4 + (lt&3)
//     lt (n 32 ct, k  8 kt): frag = ((ct>>3)*8  + kt)*8 + (ct&7)
//   A operand x[m][k]: lane = (m&15) | (((k>>3)&3)<<4), j = k&7
//     x  (m 2048 mt, k 24 kt): frag = mt*24 + kt
// ---------------------------------------------------------------------------

// ---------------------------------------------------------------------------
// Kernel 0 (prep_all): everything that depends only on inputs, one launch.
// Latency-bound small jobs FIRST so they overlap the 2048-block x-repack:
//   bid 0            : zero fusion accumulator
//   bid [1, 65)      : label-side joint GEMM (la_f / lt_f)
//   bid [65, 449)    : Wi/Wia repack -> frag f16
//   bid [449, 449+XB): x repack f32 -> f16 A-frag (LDS transpose)
// ---------------------------------------------------------------------------
__global__ __launch_bounds__(256) void prep_all(
    const float* __restrict__ x,
    const float* __restrict__ Wi, const float* __restrict__ Wia,
    const float* __restrict__ lab,
    const float* __restrict__ Wl,  const float* __restrict__ bl,
    const float* __restrict__ Wla, const float* __restrict__ bla,
    const float* __restrict__ ctx,
    unsigned short* __restrict__ x_f,
    unsigned short* __restrict__ Wi_f, unsigned short* __restrict__ Wia_f,
    unsigned short* __restrict__ la_f, unsigned short* __restrict__ lt_f,
    float* __restrict__ fusion)
{
    __shared__ unsigned short tile[16 * XP_STRIDE];   // 24.8 KB (x part only)
    const int t   = threadIdx.x;
    const int bid = blockIdx.x;

    if (bid == 0) {
        // ---- zero fusion accumulator (B*C = 8192 floats)
        float4 z = {0.f, 0.f, 0.f, 0.f};
        float4* fp = (float4*)(void*)fusion;
#pragma unroll
        for (int i = 0; i < 8; ++i) fp[i * 256 + t] = z;
        return;
    }

    if (bid < 65) {
        // ---- label-side joint GEMM (reads Wl/Wla raw f32)
        const int lbid = bid - 1;
        const int wave = t >> 6;
        const int lane = t & 63;
        const int quad = lane >> 4;
        const int c16  = lane & 15;
        const int ct2  = lbid & 7;
        const int mh   = lbid >> 3;          // 0..7
        const int ct   = ct2 * 4 + wave;     // 0..31
        const int n0   = ct * 16;
        const int l0   = mh * 32;

        const f32x4 z4 = {0.f, 0.f, 0.f, 0.f};
        f32x4 a1[2], a2[2];
#pragma unroll
        for (int mt = 0; mt < 2; ++mt) { a1[mt] = z4; a2[mt] = z4; }

        const float* lb   = lab + (size_t)(l0 + c16) * H_DIM + quad * 8;
        const float* wlp  = Wl  + (size_t)(n0 + c16) * H_DIM + quad * 8;
        const float* wlap = Wla + (size_t)(n0 + c16) * H_DIM + quad * 8;
        for (int kt = 0; kt < 24; ++kt) {
            short8 b1 = cvt8(wlp + kt * 32);
            short8 b2 = cvt8(wlap + kt * 32);
#pragma unroll
            for (int mt = 0; mt < 2; ++mt) {
                short8 a = cvt8(lb + mt * 16 * H_DIM + kt * 32);
                a1[mt] = MFMA_F16(a, b1, a1[mt]);
                a2[mt] = MFMA_F16(a, b2, a2[mt]);
            }
        }
        const int c = n0 + c16;
        const float blv = bl[c], blav = bla[c], cv = ctx[c];
#pragma unroll
        for (int mt = 0; mt < 2; ++mt)
#pragma unroll
            for (int r = 0; r < 4; ++r) {
                const int l = l0 + mt * 16 + quad * 4 + r;
                const float ltv = sigmoid_f(a1[mt][r] + blv);
                const float lav = sigmoid_f(a2[mt][r] + blav) * cv;
                {   // lt_f: n=c, k=l
                    const int ctc = c >> 4, ktl = l >> 5;
                    const int frag = ((ctc >> 3) * 8 + ktl) * 8 + (ctc & 7);
                    const int ln = (c & 15) | (((l >> 3) & 3) << 4);
                    lt_f[((size_t)frag * 64 + ln) * 8 + (l & 7)] = f2h(ltv);
                }
                {   // la_f: n=l, k=c
                    const int lt = l >> 4, ktc = c >> 5;
                    const int frag = ((lt >> 2) * 16 + ktc) * 4 + (lt & 3);
                    const int ln = (l & 15) | (((c >> 3) & 3) << 4);
                    la_f[((size_t)frag * 64 + ln) * 8 + (c & 7)] = f2h(lav);
                }
            }
        return;
    }

    if (bid < 449) {
        // ---- Wi / Wia repack
        const int tid = (bid - 65) * 256 + t;         // over 2*49152
        const int m   = tid / 49152;
        const int idx = tid - m * 49152;
        const int ct   = idx / 1536;          // 0..31
        const int rem  = idx - ct * 1536;
        const int kt   = rem >> 6;            // 0..23
        const int lane = rem & 63;
        const int row  = ct * 16 + (lane & 15);
        const int kcol = kt * 32 + (lane >> 4) * 8;
        const float* src = (m == 0 ? Wi : Wia);
        unsigned short* dst = (m == 0 ? Wi_f : Wia_f);
        short8 v = cvt8(src + (size_t)row * H_DIM + kcol);
        const int frag = ((ct >> 3) * 24 + kt) * 8 + (ct & 7);
        *(short8*)(void*)(dst + ((size_t)frag * 64 + lane) * 8) = v;
        return;
    }

    // ---- x repack: coalesced f32 reads -> LDS transpose -> frag writes
    {
        const int mt = bid - 449;                     // 0..2047, 16 rows each
        const float4* src = (const float4*)(const void*)(x + (size_t)mt * 16 * H_DIM);
#pragma unroll
        for (int i = 0; i < 12; ++i) {
            const int id  = i * 256 + t;              // 0..3071 float4 chunks
            const int row = id / 192;
            const int c4  = id - row * 192;
            float4 v = src[id];                       // consecutive lanes -> coalesced
            half2v h0 = __builtin_amdgcn_cvt_pkrtz(v.x, v.y);
            half2v h1 = __builtin_amdgcn_cvt_pkrtz(v.z, v.w);
            uint2 pk = { __builtin_bit_cast(unsigned int, h0),
                         __builtin_bit_cast(unsigned int, h1) };
            *(uint2*)(void*)(tile + row * XP_STRIDE + c4 * 4) = pk;
        }
        __syncthreads();
        const int lane = t & 63;
        const int wave = t >> 6;
#pragma unroll
        for (int q = 0; q < 6; ++q) {
            const int kt = wave * 6 + q;              // 4 waves x 6 = 24 frags
            short8 v = *(const short8*)(const void*)(
                tile + (lane & 15) * XP_STRIDE + kt * 32 + (lane >> 4) * 8);
            *(short8*)(void*)(x_f + ((size_t)(mt * 24 + kt) * 64 + lane) * 8) = v;
        }
    }
}

// ---------------------------------------------------------------------------
// Kernel 2: fused main v4. Same 64-row/8-wave/2-block-per-CU shape as v1, but
// P1 and P5 run as two nt-half passes with acc[4][2] (32 AGPR instead of 64).
// Rationale: at (512,4) the unified reg cap is 128/wave; v1's 64 VGPR +
// 64 AGPR left ZERO slack, so the compiler could not prefetch next-kt frags
// and every L2 load latency was exposed (MfmaUtil 27% vs 31.5% issue ceiling).
// The half passes re-stream x_f once more per phase (cheap, L2-resident) and
// free ~32 regs of scheduling slack. P3 softmax: 4 barriers -> 2 (separate
// sum scratch; attn-write folded into the exp step).
// ---------------------------------------------------------------------------
template<bool XF>
__global__ __launch_bounds__(512, 4) void fused_main(
    const unsigned short* __restrict__ x_f,     // A-frag f16 (XF only)
    const float* __restrict__ x,                // f32 (fallback only)
    const float* __restrict__ bi,
    const float* __restrict__ bia,
    const unsigned short* __restrict__ Wi_f,
    const unsigned short* __restrict__ Wia_f,
    const unsigned short* __restrict__ lt_f,
    const unsigned short* __restrict__ la_f,
    float* __restrict__ fusion)                 // f32 [B][C]
{
    __shared__ unsigned short lds_buf[64 * IA_STRIDE]; // 66.6 KB: ia / attn / wgt
    __shared__ float scratchA[8 * 64];                 // per-wave row maxima
    __shared__ float scratchB[8 * 64];                 // per-wave row sums
    __shared__ float inv_lds[64];

    const int tid  = threadIdx.x;
    const int wave = tid >> 6;      // 0..7
    const int lane = tid & 63;
    const int quad = lane >> 4;
    const int c16  = lane & 15;

    const int row0 = blockIdx.x * 64;
    const int b    = row0 >> 11;   // / 2048

    const f32x4 z4 = {0.f, 0.f, 0.f, 0.f};
    const int n0 = wave * 64;      // C-column split (phases 1,4,5)

    const float*  xb  = x + (size_t)(row0 + c16) * H_DIM + quad * 8;
    const short8* xf8 = (const short8*)(const void*)x_f + (size_t)blockIdx.x * 96 * 64 + lane;
    // W frag base for this wave's 4 ct's (ct = wave*4 + nt):
    const size_t wofs = ((size_t)(wave >> 1) * 192 + (size_t)(wave & 1) * 4) * 64 + lane;

    // ========== Phase 1: ia = x@Wia^T (K=768), sigmoid -> LDS =============
    // two nt-half passes, acc[4][2] = 32 AGPR each
    {
        const short8* wa8 = (const short8*)(const void*)Wia_f + wofs;
#pragma unroll 1
        for (int half = 0; half < 2; ++half) {
            f32x4 acc[4][2];
#pragma unroll
            for (int m = 0; m < 4; ++m)
#pragma unroll
                for (int j = 0; j < 2; ++j) acc[m][j] = z4;
            for (int kt = 0; kt < 24; ++kt) {
                short8 a0, a1, a2, a3;
                if constexpr (XF) {
                    a0 = xf8[kt * 64];        a1 = xf8[(24 + kt) * 64];
                    a2 = xf8[(48 + kt) * 64]; a3 = xf8[(72 + kt) * 64];
                } else {
                    a0 = cvt8(xb + kt * 32);                a1 = cvt8(xb + 16 * H_DIM + kt * 32);
                    a2 = cvt8(xb + 32 * H_DIM + kt * 32);   a3 = cvt8(xb + 48 * H_DIM + kt * 32);
                }
#pragma unroll
                for (int j = 0; j < 2; ++j) {
                    short8 bw = wa8[(kt * 8 + half * 2 + j) * 64];
                    acc[0][j] = MFMA_F16(a0, bw, acc[0][j]);
                    acc[1][j] = MFMA_F16(a1, bw, acc[1][j]);
                    acc[2][j] = MFMA_F16(a2, bw, acc[2][j]);
                    acc[3][j] = MFMA_F16(a3, bw, acc[3][j]);
                }
            }
#pragma unroll
            for (int j = 0; j < 2; ++j) {
                const int col = n0 + (half * 2 + j) * 16 + c16;
                const float bv = bia[col];
#pragma unroll
                for (int m = 0; m < 4; ++m)
#pragma unroll
                    for (int r = 0; r < 4; ++r) {
                        const int row = m * 16 + quad * 4 + r;
                        lds_buf[row * IA_STRIDE + col] = f2h(sigmoid_f(acc[m][j][r] + bv));
                    }
            }
        }
    }
    __syncthreads();

    // ========== Phase 2: logits = ia @ la^T (K=512) =======================
    const int n0l = wave * 32;   // L-column split (8 waves x 32 = 256)
    f32x4 accl[4][2];
#pragma unroll
    for (int m = 0; m < 4; ++m)
#pragma unroll
        for (int j = 0; j < 2; ++j) accl[m][j] = z4;
    {
        const unsigned short* ab = lds_buf + c16 * IA_STRIDE + quad * 8;
        const short8* la8 = (const short8*)(const void*)la_f
                          + ((size_t)(wave >> 1) * 64 + (size_t)(wave & 1) * 2) * 64 + lane;
        for (int kt = 0; kt < 16; ++kt) {
            const int kk = kt * 32;
            short8 a0 = *(const short8*)(const void*)(ab + kk);
            short8 a1 = *(const short8*)(const void*)(ab + 16 * IA_STRIDE + kk);
            short8 a2 = *(const short8*)(const void*)(ab + 32 * IA_STRIDE + kk);
            short8 a3 = *(const short8*)(const void*)(ab + 48 * IA_STRIDE + kk);
#pragma unroll
            for (int j = 0; j < 2; ++j) {
                short8 bfr = la8[(kt * 4 + j) * 64];
                accl[0][j] = MFMA_F16(a0, bfr, accl[0][j]);
                accl[1][j] = MFMA_F16(a1, bfr, accl[1][j]);
                accl[2][j] = MFMA_F16(a2, bfr, accl[2][j]);
                accl[3][j] = MFMA_F16(a3, bfr, accl[3][j]);
            }
        }
    }
    __syncthreads();   // all ia reads complete; lds_buf reusable for attn

    // ========== Phase 3: softmax over L (unnormalized; keep 1/sum) ========
    // 3a: per-wave row maxima -> scratchA
#pragma unroll
    for (int m = 0; m < 4; ++m)
#pragma unroll
        for (int r = 0; r < 4; ++r) {
            float mx = fmaxf(accl[m][0][r], accl[m][1][r]);
#pragma unroll
            for (int off = 1; off < 16; off <<= 1) mx = fmaxf(mx, __shfl_xor(mx, off, 64));
            if (c16 == 0) scratchA[wave * 64 + m * 16 + quad * 4 + r] = mx;
        }
    __syncthreads();
    // 3b: global max, exp, attn f16 -> LDS, per-wave sums -> scratchB
#pragma unroll
    for (int m = 0; m < 4; ++m)
#pragma unroll
        for (int r = 0; r < 4; ++r) {
            const int row = m * 16 + quad * 4 + r;
            float gm = scratchA[row];
#pragma unroll
            for (int w = 1; w < 8; ++w) gm = fmaxf(gm, scratchA[w * 64 + row]);
            const float e0 = __expf(accl[m][0][r] - gm);
            const float e1 = __expf(accl[m][1][r] - gm);
            lds_buf[row * ATTN_STRIDE + n0l + c16]      = f2h(e0);
            lds_buf[row * ATTN_STRIDE + n0l + 16 + c16] = f2h(e1);
            float s = e0 + e1;
#pragma unroll
            for (int off = 1; off < 16; off <<= 1) s += __shfl_xor(s, off, 64);
            if (c16 == 0) scratchB[wave * 64 + row] = s;
        }
    __syncthreads();   // attn + sums visible
    // 3c: inverse row sums -> inv_lds (read after the post-P4 barrier)
    if (wave == 0 && c16 == 0) {
#pragma unroll
        for (int m = 0; m < 4; ++m)
#pragma unroll
            for (int r = 0; r < 4; ++r) {
                const int row = m * 16 + quad * 4 + r;
                float st = 0.f;
#pragma unroll
                for (int w = 0; w < 8; ++w) st += scratchB[w * 64 + row];
                inv_lds[row] = 1.0f / st;
            }
    }

    // ========== Phase 4: weighted = attn @ lt (K=256) =====================
    f32x4 accw[4][4];
#pragma unroll
    for (int m = 0; m < 4; ++m)
#pragma unroll
        for (int nt = 0; nt < 4; ++nt) accw[m][nt] = z4;
    {
        const unsigned short* ab = lds_buf + c16 * ATTN_STRIDE + quad * 8;
        const short8* lt8 = (const short8*)(const void*)lt_f
                          + ((size_t)(wave >> 1) * 64 + (size_t)(wave & 1) * 4) * 64 + lane;
        for (int kt = 0; kt < 8; ++kt) {
            const int kk = kt * 32;
            short8 a0 = *(const short8*)(const void*)(ab + kk);
            short8 a1 = *(const short8*)(const void*)(ab + 16 * ATTN_STRIDE + kk);
            short8 a2 = *(const short8*)(const void*)(ab + 32 * ATTN_STRIDE + kk);
            short8 a3 = *(const short8*)(const void*)(ab + 48 * ATTN_STRIDE + kk);
#pragma unroll
            for (int nt = 0; nt < 4; ++nt) {
                short8 bfr = lt8[(kt * 8 + nt) * 64];
                accw[0][nt] = MFMA_F16(a0, bfr, accw[0][nt]);
                accw[1][nt] = MFMA_F16(a1, bfr, accw[1][nt]);
                accw[2][nt] = MFMA_F16(a2, bfr, accw[2][nt]);
                accw[3][nt] = MFMA_F16(a3, bfr, accw[3][nt]);
            }
        }
    }
    __syncthreads();   // all attn reads complete; lds_buf reusable for wgt

    // spill wgt = weighted * invsum to LDS (f16); wave-private cols
    {
        float invr[4][4];
#pragma unroll
        for (int m = 0; m < 4; ++m)
#pragma unroll
            for (int r = 0; r < 4; ++r) invr[m][r] = inv_lds[m * 16 + quad * 4 + r];
#pragma unroll
        for (int nt = 0; nt < 4; ++nt) {
            const int col = n0 + nt * 16 + c16;
#pragma unroll
            for (int m = 0; m < 4; ++m)
#pragma unroll
                for (int r = 0; r < 4; ++r) {
                    const int row = m * 16 + quad * 4 + r;
                    lds_buf[row * IA_STRIDE + col] = f2h(accw[m][nt][r] * invr[m][r]);
                }
        }
    }
    // no barrier: phase 5 reads only this wave's own cols

    // ========== Phase 5: it = x@Wi^T (recompute), fusion + atomics ========
    // two nt-half passes, acc[4][2] = 32 AGPR each
    {
        const short8* wi8 = (const short8*)(const void*)Wi_f + wofs;
#pragma unroll 1
        for (int half = 0; half < 2; ++half) {
            f32x4 acc[4][2];
#pragma unroll
            for (int m = 0; m < 4; ++m)
#pragma unroll
                for (int j = 0; j < 2; ++j) acc[m][j] = z4;
            for (int kt = 0; kt < 24; ++kt) {
                short8 a0, a1, a2, a3;
                if constexpr (XF) {
                    a0 = xf8[kt * 64];        a1 = xf8[(24 + kt) * 64];
                    a2 = xf8[(48 + kt) * 64]; a3 = xf8[(72 + kt) * 64];
                } else {
                    a0 = cvt8(xb + kt * 32);                a1 = cvt8(xb + 16 * H_DIM + kt * 32);
                    a2 = cvt8(xb + 32 * H_DIM + kt * 32);   a3 = cvt8(xb + 48 * H_DIM + kt * 32);
                }
#pragma unroll
                for (int j = 0; j < 2; ++j) {
                    short8 bw = wi8[(kt * 8 + half * 2 + j) * 64];
                    acc[0][j] = MFMA_F16(a0, bw, acc[0][j]);
                    acc[1][j] = MFMA_F16(a1, bw, acc[1][j]);
                    acc[2][j] = MFMA_F16(a2, bw, acc[2][j]);
                    acc[3][j] = MFMA_F16(a3, bw, acc[3][j]);
                }
            }
#pragma unroll
            for (int j = 0; j < 2; ++j) {
                const int col = n0 + (half * 2 + j) * 16 + c16;
                const float bv = bi[col];
                float s = 0.f;
#pragma unroll
                for (int m = 0; m < 4; ++m)
#pragma unroll
                    for (int r = 0; r < 4; ++r) {
                        const int row = m * 16 + quad * 4 + r;
                        s += h2f(lds_buf[row * IA_STRIDE + col]) * sigmoid_f(acc[m][j][r] + bv);
                    }
                s += __shfl_xor(s, 16, 64);
                s += __shfl_xor(s, 32, 64);
                if (lane < 16) atomicAdd(&fusion[b * C_DIM + col], s);
            }
        }
    }
}

// ---------------------------------------------------------------------------
// Kernel 3: out[b][h] = sum_c fusion[b][c] * Wp[h][c]. 8 lanes per row.
// ---------------------------------------------------------------------------
__global__ __launch_bounds__(256) void out_kernel(
    const float* __restrict__ fusion,
    const float* __restrict__ Wp,
    float* __restrict__ out)
{
    const int idx = blockIdx.x * 256 + threadIdx.x;
    const int R   = idx >> 3;
    const int sub = idx & 7;
    const int bb  = R / H_DIM;
    const int h   = R - bb * H_DIM;
    const float* wp = Wp + (size_t)h * C_DIM;
    const float* f  = fusion + bb * C_DIM;
    float s = 0.f;
#pragma unroll
    for (int j = 0; j < 16; ++j) {
        const int c = j * 32 + sub * 4;
        float4 wv = *(const float4*)(const void*)(wp + c);
        float4 fv = *(const float4*)(const void*)(f + c);
        s += fv.x * wv.x + fv.y * wv.y + fv.z * wv.z + fv.w * wv.w;
    }
    s += __shfl_xor(s, 1, 64);
    s += __shfl_xor(s, 2, 64);
    s += __shfl_xor(s, 4, 64);
    if (sub == 0) out[R] = s;
}

extern "C" void kernel_launch(void* const* d_in, const int* in_sizes, int n_in,
                              void* d_out, int out_size, void* d_ws, size_t ws_size,
                              hipStream_t stream)
{
    const float* x    = (const float*)d_in[0];
    const float* lab  = (const float*)d_in[1];
    const float* Wi   = (const float*)d_in[2];
    const float* bi   = (const float*)d_in[3];
    const float* Wl   = (const float*)d_in[4];
    const float* bl   = (const float*)d_in[5];
    const float* Wia  = (const float*)d_in[6];
    const float* bia  = (const float*)d_in[7];
    const float* Wla  = (const float*)d_in[8];
    const float* bla  = (const float*)d_in[9];
    const float* ctx  = (const float*)d_in[10];
    const float* Wp   = (const float*)d_in[11];

    char* ws = (char*)d_ws;
    unsigned short* Wi_f  = (unsigned short*)(ws);               // 768 KB
    unsigned short* Wia_f = (unsigned short*)(ws + 786432);      // 768 KB
    unsigned short* la_f  = (unsigned short*)(ws + 3145728);     // 256 KB
    unsigned short* lt_f  = (unsigned short*)(ws + 3407872);     // 256 KB
    float* fusion         = (float*)(ws + 3670016);              // 32 KB
    unsigned short* x_f   = (unsigned short*)(ws + 3702784);     // 48 MB (optional)
    const size_t NEED_XF  = 3702784 + (size_t)32768 * 768 * 2;   // ~51.5 MB

    if (ws_size >= NEED_XF) {
        // 1 zero + 64 label + 384 W + 2048 x = 2497 blocks
        prep_all<<<2497, 256, 0, stream>>>(
            x, Wi, Wia, lab, Wl, bl, Wla, bla, ctx,
            x_f, Wi_f, Wia_f, la_f, lt_f, fusion);
        fused_main<true><<<(B_DIM * S_DIM) / 64, 512, 0, stream>>>(
            x_f, x, bi, bia, Wi_f, Wia_f, lt_f, la_f, fusion);
    } else {
        prep_all<<<449, 256, 0, stream>>>(
            x, Wi, Wia, lab, Wl, bl, Wla, bla, ctx,
            nullptr, Wi_f, Wia_f, la_f, lt_f, fusion);
        fused_main<false><<<(B_DIM * S_DIM) / 64, 512, 0, stream>>>(
            nullptr, x, bi, bia, Wi_f, Wia_f, lt_f, la_f, fusion);
    }
    out_kernel<<<384, 256, 0, stream>>>(fusion, Wp, (float*)d_out);
}

// Round 9
// 286.057 us; speedup vs baseline: 1.0347x; 1.0347x over previous
//
#include <hip/hip_runtime.h>

#define H_DIM 768
#define C_DIM 512
#define L_DIM 256
#define S_DIM 2048
#define B_DIM 16

#define IA_STRIDE 520   // 512 + 8: lane stride 1040B = 260 dw = 4 mod 32 banks
#define ATTN_STRIDE 264 // 256 + 8: lane stride 528B = 132 dw = 4 mod 32 banks
#define XP_STRIDE 776   // 768 + 8 (f16): row stride 1552B, 16B-aligned, 2-way conflict (free)

typedef __attribute__((ext_vector_type(8))) short short8;
typedef __attribute__((ext_vector_type(4))) float f32x4;
typedef __attribute__((ext_vector_type(2))) __fp16 half2v;   // cvt_pkrtz return type

#define MFMA_F16(a, b, c) __builtin_amdgcn_mfma_f32_16x16x32_f16((a), (b), (c), 0, 0, 0)

__device__ __forceinline__ unsigned short f2h(float f) {
    _Float16 h = (_Float16)f;
    return __builtin_bit_cast(unsigned short, h);
}
__device__ __forceinline__ float h2f(unsigned short u) {
    _Float16 h = __builtin_bit_cast(_Float16, u);
    return (float)h;
}
__device__ __forceinline__ float sigmoid_f(float x) { return 1.0f / (1.0f + __expf(-x)); }

// load 8 consecutive f32, convert to packed f16 frag via v_cvt_pkrtz
__device__ __forceinline__ short8 cvt8(const float* p) {
    const float4* q = (const float4*)(const void*)p;
    float4 u = q[0], v = q[1];
    half2v h0 = __builtin_amdgcn_cvt_pkrtz(u.x, u.y);
    half2v h1 = __builtin_amdgcn_cvt_pkrtz(u.z, u.w);
    half2v h2 = __builtin_amdgcn_cvt_pkrtz(v.x, v.y);
    half2v h3 = __builtin_amdgcn_cvt_pkrtz(v.z, v.w);
    int4 pk = { __builtin_bit_cast(int, h0), __builtin_bit_cast(int, h1),
                __builtin_bit_cast(int, h2), __builtin_bit_cast(int, h3) };
    return __builtin_bit_cast(short8, pk);
}

// ---------------------------------------------------------------------------
// Frag layouts (one wave frag load = 64 lanes x 16 B = 1 KB contiguous):
//   B operand M[n][k]: lane = (n&15) | (((k>>3)&3)<<4), j = k&7
//     W  (n 32 ct, k 24 kt): frag = ((ct>>3)*24 + kt)*8 + (ct&7)
//     la (n 16 lt, k 16 kt): frag = ((lt>>2)*16 + kt)*4 + (lt&3)
//     lt (n 32 ct, k  8 kt): frag = ((ct>>3)*8  + kt)*8 + (ct&7)
//   A operand x[m][k]: lane = (m&15) | (((k>>3)&3)<<4), j = k&7
//     x  (m 2048 mt, k 24 kt): frag = mt*24 + kt
// ---------------------------------------------------------------------------

// ---------------------------------------------------------------------------
// Kernel 0 (prep_all): everything that depends only on inputs, one launch.
// Latency-bound small jobs FIRST so they overlap the 2048-block x-repack:
//   bid 0            : zero fusion accumulator
//   bid [1, 65)      : label-side joint GEMM (la_f / lt_f)
//   bid [65, 449)    : Wi/Wia repack -> frag f16
//   bid [449, 449+XB): x repack f32 -> f16 A-frag (LDS transpose)
// ---------------------------------------------------------------------------
__global__ __launch_bounds__(256) void prep_all(
    const float* __restrict__ x,
    const float* __restrict__ Wi, const float* __restrict__ Wia,
    const float* __restrict__ lab,
    const float* __restrict__ Wl,  const float* __restrict__ bl,
    const float* __restrict__ Wla, const float* __restrict__ bla,
    const float* __restrict__ ctx,
    unsigned short* __restrict__ x_f,
    unsigned short* __restrict__ Wi_f, unsigned short* __restrict__ Wia_f,
    unsigned short* __restrict__ la_f, unsigned short* __restrict__ lt_f,
    float* __restrict__ fusion)
{
    __shared__ unsigned short tile[16 * XP_STRIDE];   // 24.8 KB (x part only)
    const int t   = threadIdx.x;
    const int bid = blockIdx.x;

    if (bid == 0) {
        // ---- zero fusion accumulator (B*C = 8192 floats)
        float4 z = {0.f, 0.f, 0.f, 0.f};
        float4* fp = (float4*)(void*)fusion;
#pragma unroll
        for (int i = 0; i < 8; ++i) fp[i * 256 + t] = z;
        return;
    }

    if (bid < 65) {
        // ---- label-side joint GEMM (reads Wl/Wla raw f32)
        const int lbid = bid - 1;
        const int wave = t >> 6;
        const int lane = t & 63;
        const int quad = lane >> 4;
        const int c16  = lane & 15;
        const int ct2  = lbid & 7;
        const int mh   = lbid >> 3;          // 0..7
        const int ct   = ct2 * 4 + wave;     // 0..31
        const int n0   = ct * 16;
        const int l0   = mh * 32;

        const f32x4 z4 = {0.f, 0.f, 0.f, 0.f};
        f32x4 a1[2], a2[2];
#pragma unroll
        for (int mt = 0; mt < 2; ++mt) { a1[mt] = z4; a2[mt] = z4; }

        const float* lb   = lab + (size_t)(l0 + c16) * H_DIM + quad * 8;
        const float* wlp  = Wl  + (size_t)(n0 + c16) * H_DIM + quad * 8;
        const float* wlap = Wla + (size_t)(n0 + c16) * H_DIM + quad * 8;
        for (int kt = 0; kt < 24; ++kt) {
            short8 b1 = cvt8(wlp + kt * 32);
            short8 b2 = cvt8(wlap + kt * 32);
#pragma unroll
            for (int mt = 0; mt < 2; ++mt) {
                short8 a = cvt8(lb + mt * 16 * H_DIM + kt * 32);
                a1[mt] = MFMA_F16(a, b1, a1[mt]);
                a2[mt] = MFMA_F16(a, b2, a2[mt]);
            }
        }
        const int c = n0 + c16;
        const float blv = bl[c], blav = bla[c], cv = ctx[c];
#pragma unroll
        for (int mt = 0; mt < 2; ++mt)
#pragma unroll
            for (int r = 0; r < 4; ++r) {
                const int l = l0 + mt * 16 + quad * 4 + r;
                const float ltv = sigmoid_f(a1[mt][r] + blv);
                const float lav = sigmoid_f(a2[mt][r] + blav) * cv;
                {   // lt_f: n=c, k=l
                    const int ctc = c >> 4, ktl = l >> 5;
                    const int frag = ((ctc >> 3) * 8 + ktl) * 8 + (ctc & 7);
                    const int ln = (c & 15) | (((l >> 3) & 3) << 4);
                    lt_f[((size_t)frag * 64 + ln) * 8 + (l & 7)] = f2h(ltv);
                }
                {   // la_f: n=l, k=c
                    const int lt = l >> 4, ktc = c >> 5;
                    const int frag = ((lt >> 2) * 16 + ktc) * 4 + (lt & 3);
                    const int ln = (l & 15) | (((c >> 3) & 3) << 4);
                    la_f[((size_t)frag * 64 + ln) * 8 + (c & 7)] = f2h(lav);
                }
            }
        return;
    }

    if (bid < 449) {
        // ---- Wi / Wia repack
        const int tid = (bid - 65) * 256 + t;         // over 2*49152
        const int m   = tid / 49152;
        const int idx = tid - m * 49152;
        const int ct   = idx / 1536;          // 0..31
        const int rem  = idx - ct * 1536;
        const int kt   = rem >> 6;            // 0..23
        const int lane = rem & 63;
        const int row  = ct * 16 + (lane & 15);
        const int kcol = kt * 32 + (lane >> 4) * 8;
        const float* src = (m == 0 ? Wi : Wia);
        unsigned short* dst = (m == 0 ? Wi_f : Wia_f);
        short8 v = cvt8(src + (size_t)row * H_DIM + kcol);
        const int frag = ((ct >> 3) * 24 + kt) * 8 + (ct & 7);
        *(short8*)(void*)(dst + ((size_t)frag * 64 + lane) * 8) = v;
        return;
    }

    // ---- x repack: coalesced f32 reads -> LDS transpose -> frag writes
    {
        const int mt = bid - 449;                     // 0..2047, 16 rows each
        const float4* src = (const float4*)(const void*)(x + (size_t)mt * 16 * H_DIM);
#pragma unroll
        for (int i = 0; i < 12; ++i) {
            const int id  = i * 256 + t;              // 0..3071 float4 chunks
            const int row = id / 192;
            const int c4  = id - row * 192;
            float4 v = src[id];                       // consecutive lanes -> coalesced
            half2v h0 = __builtin_amdgcn_cvt_pkrtz(v.x, v.y);
            half2v h1 = __builtin_amdgcn_cvt_pkrtz(v.z, v.w);
            uint2 pk = { __builtin_bit_cast(unsigned int, h0),
                         __builtin_bit_cast(unsigned int, h1) };
            *(uint2*)(void*)(tile + row * XP_STRIDE + c4 * 4) = pk;
        }
        __syncthreads();
        const int lane = t & 63;
        const int wave = t >> 6;
#pragma unroll
        for (int q = 0; q < 6; ++q) {
            const int kt = wave * 6 + q;              // 4 waves x 6 = 24 frags
            short8 v = *(const short8*)(const void*)(
                tile + (lane & 15) * XP_STRIDE + kt * 32 + (lane >> 4) * 8);
            *(short8*)(void*)(x_f + ((size_t)(mt * 24 + kt) * 64 + lane) * 8) = v;
        }
    }
}

// ---------------------------------------------------------------------------
// Kernel 2: fused main (r7 single-pass P1/P5 acc[4][4] — the measured best —
// plus r8's 2-barrier softmax). 64 rows, 8 waves x 64 C-cols, 2 blocks/CU.
// Register note: (512,4) caps 128 unified regs/wave; acc[4][4]=64 AGPR +
// 64 VGPR is exactly full. r8 proved freeing AGPR slack does NOT make the
// compiler pipeline deeper (VGPR stayed 64) and the extra x_f stream goes to
// HBM (+44 MB FETCH) — single-pass is strictly better.
// ---------------------------------------------------------------------------
template<bool XF>
__global__ __launch_bounds__(512, 4) void fused_main(
    const unsigned short* __restrict__ x_f,     // A-frag f16 (XF only)
    const float* __restrict__ x,                // f32 (fallback only)
    const float* __restrict__ bi,
    const float* __restrict__ bia,
    const unsigned short* __restrict__ Wi_f,
    const unsigned short* __restrict__ Wia_f,
    const unsigned short* __restrict__ lt_f,
    const unsigned short* __restrict__ la_f,
    float* __restrict__ fusion)                 // f32 [B][C]
{
    __shared__ unsigned short lds_buf[64 * IA_STRIDE]; // 66.6 KB: ia / attn / wgt
    __shared__ float scratchA[8 * 64];                 // per-wave row maxima
    __shared__ float scratchB[8 * 64];                 // per-wave row sums
    __shared__ float inv_lds[64];

    const int tid  = threadIdx.x;
    const int wave = tid >> 6;      // 0..7
    const int lane = tid & 63;
    const int quad = lane >> 4;
    const int c16  = lane & 15;

    const int row0 = blockIdx.x * 64;
    const int b    = row0 >> 11;   // / 2048

    const f32x4 z4 = {0.f, 0.f, 0.f, 0.f};
    const int n0 = wave * 64;      // C-column split (phases 1,4,5)

    const float*  xb  = x + (size_t)(row0 + c16) * H_DIM + quad * 8;
    const short8* xf8 = (const short8*)(const void*)x_f + (size_t)blockIdx.x * 96 * 64 + lane;
    // W frag base for this wave's 4 ct's (ct = wave*4 + nt):
    const size_t wofs = ((size_t)(wave >> 1) * 192 + (size_t)(wave & 1) * 4) * 64 + lane;

    // ========== Phase 1: ia = x@Wia^T (K=768), sigmoid -> LDS =============
    {
        f32x4 acc[4][4];
#pragma unroll
        for (int m = 0; m < 4; ++m)
#pragma unroll
            for (int nt = 0; nt < 4; ++nt) acc[m][nt] = z4;
        const short8* wa8 = (const short8*)(const void*)Wia_f + wofs;
        for (int kt = 0; kt < 24; ++kt) {
            short8 a0, a1, a2, a3;
            if constexpr (XF) {
                a0 = xf8[kt * 64];        a1 = xf8[(24 + kt) * 64];
                a2 = xf8[(48 + kt) * 64]; a3 = xf8[(72 + kt) * 64];
            } else {
                a0 = cvt8(xb + kt * 32);                a1 = cvt8(xb + 16 * H_DIM + kt * 32);
                a2 = cvt8(xb + 32 * H_DIM + kt * 32);   a3 = cvt8(xb + 48 * H_DIM + kt * 32);
            }
#pragma unroll
            for (int nt = 0; nt < 4; ++nt) {
                short8 bw = wa8[(kt * 8 + nt) * 64];
                acc[0][nt] = MFMA_F16(a0, bw, acc[0][nt]);
                acc[1][nt] = MFMA_F16(a1, bw, acc[1][nt]);
                acc[2][nt] = MFMA_F16(a2, bw, acc[2][nt]);
                acc[3][nt] = MFMA_F16(a3, bw, acc[3][nt]);
            }
        }
#pragma unroll
        for (int nt = 0; nt < 4; ++nt) {
            const int col = n0 + nt * 16 + c16;
            const float bv = bia[col];
#pragma unroll
            for (int m = 0; m < 4; ++m)
#pragma unroll
                for (int r = 0; r < 4; ++r) {
                    const int row = m * 16 + quad * 4 + r;
                    lds_buf[row * IA_STRIDE + col] = f2h(sigmoid_f(acc[m][nt][r] + bv));
                }
        }
    }
    __syncthreads();

    // ========== Phase 2: logits = ia @ la^T (K=512) =======================
    const int n0l = wave * 32;   // L-column split (8 waves x 32 = 256)
    f32x4 accl[4][2];
#pragma unroll
    for (int m = 0; m < 4; ++m)
#pragma unroll
        for (int j = 0; j < 2; ++j) accl[m][j] = z4;
    {
        const unsigned short* ab = lds_buf + c16 * IA_STRIDE + quad * 8;
        const short8* la8 = (const short8*)(const void*)la_f
                          + ((size_t)(wave >> 1) * 64 + (size_t)(wave & 1) * 2) * 64 + lane;
        for (int kt = 0; kt < 16; ++kt) {
            const int kk = kt * 32;
            short8 a0 = *(const short8*)(const void*)(ab + kk);
            short8 a1 = *(const short8*)(const void*)(ab + 16 * IA_STRIDE + kk);
            short8 a2 = *(const short8*)(const void*)(ab + 32 * IA_STRIDE + kk);
            short8 a3 = *(const short8*)(const void*)(ab + 48 * IA_STRIDE + kk);
#pragma unroll
            for (int j = 0; j < 2; ++j) {
                short8 bfr = la8[(kt * 4 + j) * 64];
                accl[0][j] = MFMA_F16(a0, bfr, accl[0][j]);
                accl[1][j] = MFMA_F16(a1, bfr, accl[1][j]);
                accl[2][j] = MFMA_F16(a2, bfr, accl[2][j]);
                accl[3][j] = MFMA_F16(a3, bfr, accl[3][j]);
            }
        }
    }
    __syncthreads();   // all ia reads complete; lds_buf reusable for attn

    // ========== Phase 3: softmax over L (2 barriers) ======================
    // 3a: per-wave row maxima -> scratchA
#pragma unroll
    for (int m = 0; m < 4; ++m)
#pragma unroll
        for (int r = 0; r < 4; ++r) {
            float mx = fmaxf(accl[m][0][r], accl[m][1][r]);
#pragma unroll
            for (int off = 1; off < 16; off <<= 1) mx = fmaxf(mx, __shfl_xor(mx, off, 64));
            if (c16 == 0) scratchA[wave * 64 + m * 16 + quad * 4 + r] = mx;
        }
    __syncthreads();
    // 3b: global max, exp, attn f16 -> LDS, per-wave sums -> scratchB
#pragma unroll
    for (int m = 0; m < 4; ++m)
#pragma unroll
        for (int r = 0; r < 4; ++r) {
            const int row = m * 16 + quad * 4 + r;
            float gm = scratchA[row];
#pragma unroll
            for (int w = 1; w < 8; ++w) gm = fmaxf(gm, scratchA[w * 64 + row]);
            const float e0 = __expf(accl[m][0][r] - gm);
            const float e1 = __expf(accl[m][1][r] - gm);
            lds_buf[row * ATTN_STRIDE + n0l + c16]      = f2h(e0);
            lds_buf[row * ATTN_STRIDE + n0l + 16 + c16] = f2h(e1);
            float s = e0 + e1;
#pragma unroll
            for (int off = 1; off < 16; off <<= 1) s += __shfl_xor(s, off, 64);
            if (c16 == 0) scratchB[wave * 64 + row] = s;
        }
    __syncthreads();   // attn + sums visible
    // 3c: inverse row sums -> inv_lds (written by wave 0, read only after
    // the post-P4 barrier, so no extra barrier needed here)
    if (wave == 0 && c16 == 0) {
#pragma unroll
        for (int m = 0; m < 4; ++m)
#pragma unroll
            for (int r = 0; r < 4; ++r) {
                const int row = m * 16 + quad * 4 + r;
                float st = 0.f;
#pragma unroll
                for (int w = 0; w < 8; ++w) st += scratchB[w * 64 + row];
                inv_lds[row] = 1.0f / st;
            }
    }

    // ========== Phase 4: weighted = attn @ lt (K=256) =====================
    f32x4 accw[4][4];
#pragma unroll
    for (int m = 0; m < 4; ++m)
#pragma unroll
        for (int nt = 0; nt < 4; ++nt) accw[m][nt] = z4;
    {
        const unsigned short* ab = lds_buf + c16 * ATTN_STRIDE + quad * 8;
        const short8* lt8 = (const short8*)(const void*)lt_f
                          + ((size_t)(wave >> 1) * 64 + (size_t)(wave & 1) * 4) * 64 + lane;
        for (int kt = 0; kt < 8; ++kt) {
            const int kk = kt * 32;
            short8 a0 = *(const short8*)(const void*)(ab + kk);
            short8 a1 = *(const short8*)(const void*)(ab + 16 * ATTN_STRIDE + kk);
            short8 a2 = *(const short8*)(const void*)(ab + 32 * ATTN_STRIDE + kk);
            short8 a3 = *(const short8*)(const void*)(ab + 48 * ATTN_STRIDE + kk);
#pragma unroll
            for (int nt = 0; nt < 4; ++nt) {
                short8 bfr = lt8[(kt * 8 + nt) * 64];
                accw[0][nt] = MFMA_F16(a0, bfr, accw[0][nt]);
                accw[1][nt] = MFMA_F16(a1, bfr, accw[1][nt]);
                accw[2][nt] = MFMA_F16(a2, bfr, accw[2][nt]);
                accw[3][nt] = MFMA_F16(a3, bfr, accw[3][nt]);
            }
        }
    }
    __syncthreads();   // all attn reads complete; lds_buf reusable for wgt

    // spill wgt = weighted * invsum to LDS (f16); wave-private cols
    {
        float invr[4][4];
#pragma unroll
        for (int m = 0; m < 4; ++m)
#pragma unroll
            for (int r = 0; r < 4; ++r) invr[m][r] = inv_lds[m * 16 + quad * 4 + r];
#pragma unroll
        for (int nt = 0; nt < 4; ++nt) {
            const int col = n0 + nt * 16 + c16;
#pragma unroll
            for (int m = 0; m < 4; ++m)
#pragma unroll
                for (int r = 0; r < 4; ++r) {
                    const int row = m * 16 + quad * 4 + r;
                    lds_buf[row * IA_STRIDE + col] = f2h(accw[m][nt][r] * invr[m][r]);
                }
        }
    }
    // no barrier: phase 5 reads only this wave's own cols

    // ========== Phase 5: it = x@Wi^T, fusion + atomics ====================
    {
        f32x4 acc[4][4];
#pragma unroll
        for (int m = 0; m < 4; ++m)
#pragma unroll
            for (int nt = 0; nt < 4; ++nt) acc[m][nt] = z4;
        const short8* wi8 = (const short8*)(const void*)Wi_f + wofs;
        for (int kt = 0; kt < 24; ++kt) {
            short8 a0, a1, a2, a3;
            if constexpr (XF) {
                a0 = xf8[kt * 64];        a1 = xf8[(24 + kt) * 64];
                a2 = xf8[(48 + kt) * 64]; a3 = xf8[(72 + kt) * 64];
            } else {
                a0 = cvt8(xb + kt * 32);                a1 = cvt8(xb + 16 * H_DIM + kt * 32);
                a2 = cvt8(xb + 32 * H_DIM + kt * 32);   a3 = cvt8(xb + 48 * H_DIM + kt * 32);
            }
#pragma unroll
            for (int nt = 0; nt < 4; ++nt) {
                short8 bw = wi8[(kt * 8 + nt) * 64];
                acc[0][nt] = MFMA_F16(a0, bw, acc[0][nt]);
                acc[1][nt] = MFMA_F16(a1, bw, acc[1][nt]);
                acc[2][nt] = MFMA_F16(a2, bw, acc[2][nt]);
                acc[3][nt] = MFMA_F16(a3, bw, acc[3][nt]);
            }
        }
#pragma unroll
        for (int nt = 0; nt < 4; ++nt) {
            const int col = n0 + nt * 16 + c16;
            const float bv = bi[col];
            float s = 0.f;
#pragma unroll
            for (int m = 0; m < 4; ++m)
#pragma unroll
                for (int r = 0; r < 4; ++r) {
                    const int row = m * 16 + quad * 4 + r;
                    s += h2f(lds_buf[row * IA_STRIDE + col]) * sigmoid_f(acc[m][nt][r] + bv);
                }
            s += __shfl_xor(s, 16, 64);
            s += __shfl_xor(s, 32, 64);
            if (lane < 16) atomicAdd(&fusion[b * C_DIM + col], s);
        }
    }
}

// ---------------------------------------------------------------------------
// Kernel 3: out[b][h] = sum_c fusion[b][c] * Wp[h][c]. 8 lanes per row.
// ---------------------------------------------------------------------------
__global__ __launch_bounds__(256) void out_kernel(
    const float* __restrict__ fusion,
    const float* __restrict__ Wp,
    float* __restrict__ out)
{
    const int idx = blockIdx.x * 256 + threadIdx.x;
    const int R   = idx >> 3;
    const int sub = idx & 7;
    const int bb  = R / H_DIM;
    const int h   = R - bb * H_DIM;
    const float* wp = Wp + (size_t)h * C_DIM;
    const float* f  = fusion + bb * C_DIM;
    float s = 0.f;
#pragma unroll
    for (int j = 0; j < 16; ++j) {
        const int c = j * 32 + sub * 4;
        float4 wv = *(const float4*)(const void*)(wp + c);
        float4 fv = *(const float4*)(const void*)(f + c);
        s += fv.x * wv.x + fv.y * wv.y + fv.z * wv.z + fv.w * wv.w;
    }
    s += __shfl_xor(s, 1, 64);
    s += __shfl_xor(s, 2, 64);
    s += __shfl_xor(s, 4, 64);
    if (sub == 0) out[R] = s;
}

extern "C" void kernel_launch(void* const* d_in, const int* in_sizes, int n_in,
                              void* d_out, int out_size, void* d_ws, size_t ws_size,
                              hipStream_t stream)
{
    const float* x    = (const float*)d_in[0];
    const float* lab  = (const float*)d_in[1];
    const float* Wi   = (const float*)d_in[2];
    const float* bi   = (const float*)d_in[3];
    const float* Wl   = (const float*)d_in[4];
    const float* bl   = (const float*)d_in[5];
    const float* Wia  = (const float*)d_in[6];
    const float* bia  = (const float*)d_in[7];
    const float* Wla  = (const float*)d_in[8];
    const float* bla  = (const float*)d_in[9];
    const float* ctx  = (const float*)d_in[10];
    const float* Wp   = (const float*)d_in[11];

    char* ws = (char*)d_ws;
    unsigned short* Wi_f  = (unsigned short*)(ws);               // 768 KB
    unsigned short* Wia_f = (unsigned short*)(ws + 786432);      // 768 KB
    unsigned short* la_f  = (unsigned short*)(ws + 3145728);     // 256 KB
    unsigned short* lt_f  = (unsigned short*)(ws + 3407872);     // 256 KB
    float* fusion         = (float*)(ws + 3670016);              // 32 KB
    unsigned short* x_f   = (unsigned short*)(ws + 3702784);     // 48 MB (optional)
    const size_t NEED_XF  = 3702784 + (size_t)32768 * 768 * 2;   // ~51.5 MB

    if (ws_size >= NEED_XF) {
        // 1 zero + 64 label + 384 W + 2048 x = 2497 blocks
        prep_all<<<2497, 256, 0, stream>>>(
            x, Wi, Wia, lab, Wl, bl, Wla, bla, ctx,
            x_f, Wi_f, Wia_f, la_f, lt_f, fusion);
        fused_main<true><<<(B_DIM * S_DIM) / 64, 512, 0, stream>>>(
            x_f, x, bi, bia, Wi_f, Wia_f, lt_f, la_f, fusion);
    } else {
        prep_all<<<449, 256, 0, stream>>>(
            x, Wi, Wia, lab, Wl, bl, Wla, bla, ctx,
            nullptr, Wi_f, Wia_f, la_f, lt_f, fusion);
        fused_main<false><<<(B_DIM * S_DIM) / 64, 512, 0, stream>>>(
            nullptr, x, bi, bia, Wi_f, Wia_f, lt_f, la_f, fusion);
    }
    out_kernel<<<384, 256, 0, stream>>>(fusion, Wp, (float*)d_out);
}